// Round 5
// baseline (464.206 us; speedup 1.0000x reference)
//
#include <hip/hip_runtime.h>
#include <hip/hip_bf16.h>
#include <stdint.h>

#define NB 512
#define NL 128
#define ND 512

typedef __bf16 bf16;
typedef __bf16 bf16x8 __attribute__((ext_vector_type(8)));
typedef float  f32x4  __attribute__((ext_vector_type(4)));

// ------- K1: gather embed rows -> bf16 + partial sumsq; y==2: att^T ------
__global__ __launch_bounds__(256) void k_gather(const int* __restrict__ ctx1,
                                                const int* __restrict__ ctx2,
                                                const float* __restrict__ table,
                                                bf16* __restrict__ d1,
                                                bf16* __restrict__ d2,
                                                float* __restrict__ ss,
                                                const float* __restrict__ att,
                                                bf16* __restrict__ attT) {
    const int b = blockIdx.x, side = blockIdx.y, zc = blockIdx.z, t = threadIdx.x;
    if (side == 2) {                      // att transpose slice
        int chunk = b * 8 + zc;
        if (chunk < 1024) {
            int i = chunk * 256 + t;      // over 512*512
            int n = i >> 9, k = i & 511;
            attT[i] = (bf16)att[k * 512 + n];
        }
        return;
    }
    const int* __restrict__ ctx = side ? ctx2 : ctx1;
    bf16* __restrict__ dst = side ? d2 : d1;
    const int base = b * NL;
    const int dv = t & 127, lr = t >> 7;
    float acc = 0.f;
    #pragma unroll
    for (int i = 0; i < 8; ++i) {
        int l = zc * 16 + i * 2 + lr;
        int idx = ctx[base + l];
        float4 v = ((const float4*)table)[(size_t)idx * (ND / 4) + dv];
        acc += v.x * v.x + v.y * v.y + v.z * v.z + v.w * v.w;
        union { bf16 h[4]; uint2 u; } pk;
        pk.h[0] = (bf16)v.x; pk.h[1] = (bf16)v.y;
        pk.h[2] = (bf16)v.z; pk.h[3] = (bf16)v.w;
        *((uint2*)(dst + (size_t)(base + l) * ND) + dv) = pk.u;
    }
    for (int o = 32; o; o >>= 1) acc += __shfl_xor(acc, o);
    __shared__ float red[4];
    if ((t & 63) == 0) red[t >> 6] = acc;
    __syncthreads();
    if (t == 0) atomicAdd(&ss[side * NB + b], red[0] + red[1] + red[2] + red[3]);
}

// ---- FUSED: per batch b (grid 512 = 2 blk/CU):
//   for nc in 0..3: Tc(128x128) = A[b] @ attT[nc]^T  (regs -> LDS bf16)
//                   Sacc += Tc @ B[b][:, nc-slice]^T (K=128 from LDS)
//   then tanh/S-store/sums/softmax/weighted-sums/logit epilogue.
// T never touches HBM (saves 134 MB round-trip vs split kernels).
__global__ __launch_bounds__(256) void k_fused(
        const bf16* __restrict__ A, const bf16* __restrict__ attT,
        const bf16* __restrict__ Bb,
        float* __restrict__ Sout, const float* __restrict__ ss,
        const float* __restrict__ w_pred, const float* __restrict__ b_pred,
        float* __restrict__ logits) {
    const int b = blockIdx.x;
    const int row0 = b * NL;

    __shared__ __align__(16) char smem[65536];
    bf16* As = (bf16*)smem;              // 16 KB staging (also pA in epilogue)
    bf16* Bs = (bf16*)(smem + 16384);    // 16 KB staging (also pB)
    bf16* Tc = (bf16*)(smem + 32768);    // 32 KB [128][128] XOR-swizzled
    float* pA = (float*)smem;
    float* pB = (float*)(smem + 16384);
    __shared__ float rowb[2][NL], colb[2][NL];
    __shared__ float wrow[NL], wcol[NL];

    const int tid = threadIdx.x;
    const int lane = tid & 63, w = tid >> 6;
    const int lm = lane & 15, quad = lane >> 4;
    const int wm = (w & 1) * 64, wn = (w >> 1) * 64;

    f32x4 acc2[4][4] = {};               // S accumulator (persists over nc)

    for (int nc = 0; nc < 4; ++nc) {
        const int n0 = nc * 128;
        f32x4 acc1[4][4] = {};           // T-chunk accumulator

        // ---- GEMM1 chunk: Tc = A[b] @ attT[n0..n0+128]^T ----
        for (int k0 = 0; k0 < ND; k0 += 64) {
            #pragma unroll
            for (int i = 0; i < 4; ++i) {
                int s = w * 256 + i * 64 + lane;
                int r = s >> 3;
                int c = (s & 7) ^ (r & 7);
                __builtin_amdgcn_global_load_lds(
                    (const __attribute__((address_space(1))) void*)(A + (size_t)(row0 + r) * ND + k0 + c * 8),
                    (__attribute__((address_space(3))) void*)(As + (size_t)(w * 256 + i * 64) * 8),
                    16, 0, 0);
                __builtin_amdgcn_global_load_lds(
                    (const __attribute__((address_space(1))) void*)(attT + (size_t)(n0 + r) * ND + k0 + c * 8),
                    (__attribute__((address_space(3))) void*)(Bs + (size_t)(w * 256 + i * 64) * 8),
                    16, 0, 0);
            }
            __syncthreads();
            #pragma unroll
            for (int kk = 0; kk < 2; ++kk) {
                bf16x8 af[4], bfm[4];
                const int ca = (kk * 4 + quad) ^ (lm & 7);
                #pragma unroll
                for (int t4 = 0; t4 < 4; ++t4) {
                    af[t4]  = *(const bf16x8*)&As[(wm + t4 * 16 + lm) * 64 + ca * 8];
                    bfm[t4] = *(const bf16x8*)&Bs[(wn + t4 * 16 + lm) * 64 + ca * 8];
                }
                #pragma unroll
                for (int im = 0; im < 4; ++im)
                    #pragma unroll
                    for (int jn = 0; jn < 4; ++jn)
                        acc1[im][jn] = __builtin_amdgcn_mfma_f32_16x16x32_bf16(
                            af[im], bfm[jn], acc1[im][jn], 0, 0, 0);
            }
            __syncthreads();
        }

        // ---- spill T-chunk to LDS (bf16, XOR-swizzled 16B chunks) ----
        #pragma unroll
        for (int im = 0; im < 4; ++im)
        #pragma unroll
        for (int jn = 0; jn < 4; ++jn)
        #pragma unroll
        for (int p = 0; p < 4; ++p) {
            int m  = wm + im * 16 + quad * 4 + p;
            int k2 = wn + jn * 16 + lm;
            int phys = (k2 >> 3) ^ (m & 7);
            Tc[m * 128 + phys * 8 + (k2 & 7)] = (bf16)acc1[im][jn][p];
        }
        // ---- stage B[b][:, n0..n0+128] : k2 0..63 -> As, 64..127 -> Bs ----
        #pragma unroll
        for (int i = 0; i < 4; ++i) {
            int s = w * 256 + i * 64 + lane;
            int r = s >> 3;
            int c = (s & 7) ^ (r & 7);
            __builtin_amdgcn_global_load_lds(
                (const __attribute__((address_space(1))) void*)(Bb + (size_t)(row0 + r) * ND + n0 + c * 8),
                (__attribute__((address_space(3))) void*)(As + (size_t)(w * 256 + i * 64) * 8),
                16, 0, 0);
            __builtin_amdgcn_global_load_lds(
                (const __attribute__((address_space(1))) void*)(Bb + (size_t)(row0 + r) * ND + n0 + 64 + c * 8),
                (__attribute__((address_space(3))) void*)(Bs + (size_t)(w * 256 + i * 64) * 8),
                16, 0, 0);
        }
        __syncthreads();

        // ---- GEMM2 partial: Sacc += Tc @ Bc^T  (K = 128) ----
        #pragma unroll
        for (int kk2 = 0; kk2 < 4; ++kk2) {
            const bf16* buf = (kk2 < 2) ? As : Bs;
            bf16x8 af[4], bfm[4];
            const int cb = ((kk2 & 1) * 4 + quad) ^ (lm & 7);
            #pragma unroll
            for (int t4 = 0; t4 < 4; ++t4) {
                int rowA = wm + t4 * 16 + lm;
                int physA = (kk2 * 4 + quad) ^ (rowA & 7);
                af[t4]  = *(const bf16x8*)&Tc[rowA * 128 + physA * 8];
                bfm[t4] = *(const bf16x8*)&buf[(wn + t4 * 16 + lm) * 64 + cb * 8];
            }
            #pragma unroll
            for (int im = 0; im < 4; ++im)
                #pragma unroll
                for (int jn = 0; jn < 4; ++jn)
                    acc2[im][jn] = __builtin_amdgcn_mfma_f32_16x16x32_bf16(
                        af[im], bfm[jn], acc2[im][jn], 0, 0, 0);
        }
        __syncthreads();
    }

    // ---- epilogue: tanh + S store + row/col sums ----
    const float sc = rsqrtf(ss[b] * ss[NB + b]);   // 1/(na*nb), deferred norm
    float* __restrict__ Sb = Sout + (size_t)b * NL * NL;
    #pragma unroll
    for (int im = 0; im < 4; ++im)
    #pragma unroll
    for (int jn = 0; jn < 4; ++jn)
    #pragma unroll
    for (int p = 0; p < 4; ++p) {
        float v = tanhf(acc2[im][jn][p] * sc);
        acc2[im][jn][p] = v;
        int m = wm + im * 16 + quad * 4 + p;   // C/D: col=lane&15, row=quad*4+reg
        int n = wn + jn * 16 + lm;
        __builtin_nontemporal_store(v, &Sb[m * NL + n]);
    }
    #pragma unroll
    for (int im = 0; im < 4; ++im)
    #pragma unroll
    for (int p = 0; p < 4; ++p) {
        float r = acc2[im][0][p] + acc2[im][1][p] + acc2[im][2][p] + acc2[im][3][p];
        r += __shfl_xor(r, 1); r += __shfl_xor(r, 2);
        r += __shfl_xor(r, 4); r += __shfl_xor(r, 8);
        if (lm == 0) rowb[wn >> 6][wm + im * 16 + quad * 4 + p] = r;
    }
    #pragma unroll
    for (int jn = 0; jn < 4; ++jn) {
        float cv = 0.f;
        #pragma unroll
        for (int im = 0; im < 4; ++im)
            #pragma unroll
            for (int p = 0; p < 4; ++p) cv += acc2[im][jn][p];
        cv += __shfl_xor(cv, 16); cv += __shfl_xor(cv, 32);
        if (quad == 0) colb[wm >> 6][wn + jn * 16 + lm] = cv;
    }
    __syncthreads();

    // ---- softmax over means (wave0: rows, wave1: cols) ----
    if (tid < 64) {
        float a  = (rowb[0][tid] + rowb[1][tid]) * (1.f / NL);
        float c2 = (rowb[0][tid + 64] + rowb[1][tid + 64]) * (1.f / NL);
        float mx = fmaxf(a, c2);
        for (int o = 32; o; o >>= 1) mx = fmaxf(mx, __shfl_xor(mx, o));
        float e0 = expf(a - mx), e1 = expf(c2 - mx);
        float s = e0 + e1;
        for (int o = 32; o; o >>= 1) s += __shfl_xor(s, o);
        float inv = 1.f / s;
        wrow[tid] = e0 * inv; wrow[tid + 64] = e1 * inv;
    } else if (tid < 128) {
        int q = tid - 64;
        float a  = (colb[0][q] + colb[1][q]) * (1.f / NL);
        float c2 = (colb[0][q + 64] + colb[1][q + 64]) * (1.f / NL);
        float mx = fmaxf(a, c2);
        for (int o = 32; o; o >>= 1) mx = fmaxf(mx, __shfl_xor(mx, o));
        float e0 = expf(a - mx), e1 = expf(c2 - mx);
        float s = e0 + e1;
        for (int o = 32; o; o >>= 1) s += __shfl_xor(s, o);
        float inv = 1.f / s;
        wcol[q] = e0 * inv; wcol[q + 64] = e1 * inv;
    }
    __syncthreads();

    // ---- weighted sums of A/B rows (L2-hot; reuses As/Bs as pA/pB) ----
    const int c = tid & 63, g = tid >> 6;
    const bf16* __restrict__ Abase = A  + (size_t)b * NL * ND;
    const bf16* __restrict__ Bbase = Bb + (size_t)b * NL * ND;
    float aacc[8] = {}, bacc[8] = {};
    for (int l = g; l < NL; l += 4) {
        float wr = wrow[l], wc = wcol[l];
        bf16x8 va = *(const bf16x8*)(Abase + (size_t)l * ND + c * 8);
        bf16x8 vb = *(const bf16x8*)(Bbase + (size_t)l * ND + c * 8);
        #pragma unroll
        for (int j = 0; j < 8; ++j) {
            aacc[j] += wr * (float)va[j];
            bacc[j] += wc * (float)vb[j];
        }
    }
    #pragma unroll
    for (int j = 0; j < 8; ++j) {
        pA[g * ND + c * 8 + j] = aacc[j];
        pB[g * ND + c * 8 + j] = bacc[j];
    }
    __syncthreads();

    if (tid < 64) {
        float dot = 0.f;
        #pragma unroll
        for (int j = 0; j < 8; ++j) {
            int d = tid * 8 + j;
            float na = pA[0 * ND + d] + pA[1 * ND + d] + pA[2 * ND + d] + pA[3 * ND + d];
            float nb = pB[0 * ND + d] + pB[1 * ND + d] + pB[2 * ND + d] + pB[3 * ND + d];
            dot += na * nb * w_pred[d];
        }
        for (int o = 32; o; o >>= 1) dot += __shfl_xor(dot, o);
        if (tid == 0)
            logits[b] = dot * rsqrtf(ss[b]) * rsqrtf(ss[NB + b]) + b_pred[0];
    }
}

extern "C" void kernel_launch(void* const* d_in, const int* in_sizes, int n_in,
                              void* d_out, int out_size, void* d_ws, size_t ws_size,
                              hipStream_t stream) {
    const int*   t1c = (const int*)d_in[2];
    const int*   t2c = (const int*)d_in[3];
    const float* emb = (const float*)d_in[4];
    const float* att = (const float*)d_in[5];
    const float* wp  = (const float*)d_in[6];
    const float* bp  = (const float*)d_in[7];

    float* out    = (float*)d_out;
    float* logits = out;
    float* S      = out + NB;      // outputs: logits(512) then S(512*128*128)

    char* ws = (char*)d_ws;
    bf16*  Ab   = (bf16*)(ws);                              // 67,108,864 B
    bf16*  Bb   = (bf16*)(ws + 67108864);                   // 67,108,864 B
    bf16*  attT = (bf16*)(ws + 134217728);                  //    524,288 B
    float* ss   = (float*)(ws + 134742016);                 //      4,096 B

    hipMemsetAsync(ss, 0, 4096, stream);
    // gather (y=0,1) + att transpose (y=2) in one launch
    k_gather<<<dim3(NB, 3, 8), 256, 0, stream>>>(t1c, t2c, emb, Ab, Bb, ss, att, attT);
    // fused gemm1 + gemm2 + softmax/pred; T stays in LDS
    k_fused<<<dim3(NB), 256, 0, stream>>>(Ab, attT, Bb, S, ss, wp, bp, logits);
}